// Round 4
// baseline (969.670 us; speedup 1.0000x reference)
//
#include <hip/hip_runtime.h>
#include <hip/hip_fp16.h>
#include <cstddef>
#include <cstdint>

static constexpr int NN   = 50000;   // nodes
static constexpr int NE   = 800000;  // edges (without self loops)
static constexpr int NG   = 256;     // graphs
static constexpr int FIN  = 128;
static constexpr int HID  = 256;
static constexpr int EMB  = 128;
static constexpr int NGRP = 16;
static constexpr int NFAM = 128;
static constexpr int NETOT = NE + NN;  // edges + self loops

// packed edge entry: low 16 bits = src node (NN < 65536), high 16 = fp16 weight
__device__ __forceinline__ uint32_t pack_sw(int s, float w) {
    return (uint32_t)s | ((uint32_t)__half_as_ushort(__float2half(w)) << 16);
}
__device__ __forceinline__ void unpack_sw(uint32_t v, int& s, float& w) {
    s = (int)(v & 0xFFFFu);
    w = __half2float(__ushort_as_half((unsigned short)(v >> 16)));
}

// ---------------- degree / CSR build (self-loops included, dst-sorted => graph-contiguous) --

__global__ void k_init_deg(int* __restrict__ degi, int n) {
    int i = blockIdx.x * blockDim.x + threadIdx.x;
    if (i < n) degi[i] = 1;  // self loop
}

__global__ void k_count(const int* __restrict__ edst, int* __restrict__ degi, int e) {
    int i = blockIdx.x * blockDim.x + threadIdx.x;
    if (i < e) atomicAdd(degi + edst[i], 1);
}

// dinv + gstart + zero(pooled) merged
__global__ void k_prep(const int* __restrict__ degi, const int* __restrict__ batch,
                       float* __restrict__ dinv, int* __restrict__ gstart,
                       float* __restrict__ pooled, int n, int G) {
    int i = blockIdx.x * blockDim.x + threadIdx.x;
    if (i < NG * HID) pooled[i] = 0.f;
    if (i >= n) return;
    dinv[i] = rsqrtf((float)degi[i]);
    int b  = batch[i];
    int pb = (i == 0) ? -1 : batch[i - 1];
    for (int g = pb + 1; g <= b; ++g) gstart[g] = i;
    if (i == n - 1) {
        for (int g = b + 1; g <= G; ++g) gstart[g] = n;
    }
}

// rcnt + exclusive scan of degi -> row_ptr; cursor init 1 (slot 0 = self loop)
__global__ __launch_bounds__(1024) void k_scan(const int* __restrict__ degi,
                                               const int* __restrict__ gstart,
                                               float* __restrict__ rcnt,
                                               int* __restrict__ row_ptr,
                                               int* __restrict__ cursor, int n) {
    const int t = threadIdx.x;
    if (t < NG) {
        int c = gstart[t + 1] - gstart[t];
        rcnt[t] = 1.0f / (float)max(c, 1);
    }
    __shared__ int ps[1024];
    const int CH = (n + 1023) / 1024;
    int lo = t * CH;
    int hi = min(lo + CH, n);
    int s = 0;
    for (int i = lo; i < hi; ++i) s += degi[i];
    ps[t] = s;
    __syncthreads();
    for (int off = 1; off < 1024; off <<= 1) {
        int v = (t >= off) ? ps[t - off] : 0;
        __syncthreads();
        if (t >= off) ps[t] += v;
        __syncthreads();
    }
    int run = (t == 0) ? 0 : ps[t - 1];
    for (int i = lo; i < hi; ++i) {
        row_ptr[i] = run;
        cursor[i]  = 1;
        run += degi[i];
    }
    if (t == 1023) row_ptr[n] = ps[1023];
}

// build packed edge arrays: eA = (src, dinv[src]) for layer-1; eP = (src, wpool) for pool
__global__ void k_build(const int* __restrict__ esrc, const int* __restrict__ edst,
                        const int* __restrict__ batch, const float* __restrict__ dinv,
                        const float* __restrict__ rcnt, const int* __restrict__ row_ptr,
                        int* __restrict__ cursor, uint32_t* __restrict__ eA,
                        uint32_t* __restrict__ eP, int n, int e) {
    int i = blockIdx.x * blockDim.x + threadIdx.x;
    if (i < n) {
        int p = row_ptr[i];
        float di = dinv[i];
        eA[p] = pack_sw(i, di);
        eP[p] = pack_sw(i, di * di * rcnt[batch[i]]);
    } else if (i < n + e) {
        int ei = i - n;
        int d = edst[ei], s = esrc[ei];
        int p = atomicAdd(cursor + d, 1);
        int idx = row_ptr[d] + p;
        float ds = dinv[s];
        eA[idx] = pack_sw(s, ds);
        eP[idx] = pack_sw(s, dinv[d] * ds * rcnt[batch[d]]);
    }
}

// ---------------- layer-1 gather, feature-chunked + XCD-pinned ----------------
// chunk = blk&7 -> one 16-float slice of x (3.2 MB) per XCD L2.
// xa[i] = dinv[i] * sum_j w_j * x[col_j]   (self loop included in CSR)

__global__ __launch_bounds__(256) void k_agg(
        const float* __restrict__ x, const int* __restrict__ row_ptr,
        const uint32_t* __restrict__ eA, const float* __restrict__ dinv,
        float* __restrict__ xa, int n) {
    const int chunk = blockIdx.x & 7;
    const int nb    = blockIdx.x >> 3;
    const int c0    = chunk * 16;
    const int f     = threadIdx.x & 15;
    const int slot  = threadIdx.x >> 4;  // 0..15
#pragma unroll
    for (int outer = 0; outer < 4; ++outer) {
        int node = nb * 64 + outer * 16 + slot;
        if (node >= n) continue;
        float acc = 0.f;
        int beg = row_ptr[node], end = row_ptr[node + 1];
        for (int j = beg; j < end; ++j) {
            uint32_t v = __builtin_nontemporal_load(eA + j);
            int s; float w;
            unpack_sw(v, s, w);
            acc += w * x[((size_t)s << 7) + c0 + f];
        }
        __builtin_nontemporal_store(dinv[node] * acc, xa + ((size_t)node << 7) + c0 + f);
    }
}

// ---------------- fp32 tiled GEMM: C = relu(A @ W + bias) ----------------

template <bool RELU>
__global__ __launch_bounds__(256) void k_gemm_bias(
        const float* __restrict__ A, const float* __restrict__ W,
        const float* __restrict__ bias, float* __restrict__ C,
        int M, int N, int K) {
    __shared__ float As[64][68];
    __shared__ float Ws[64][68];
    const int t  = threadIdx.x;
    const int tx = t & 15;
    const int ty = t >> 4;
    const int m0 = blockIdx.x * 64;
    const int n0 = blockIdx.y * 64;

    float acc[4][4] = {};

    for (int k0 = 0; k0 < K; k0 += 64) {
#pragma unroll
        for (int l = 0; l < 4; ++l) {
            int lin = t + l * 256;
            int r   = lin >> 4;
            int c4  = (lin & 15) << 2;
            float4 av = make_float4(0.f, 0.f, 0.f, 0.f);
            int gr = m0 + r;
            if (gr < M) av = *(const float4*)(A + (size_t)gr * K + k0 + c4);
            *(float4*)&As[r][c4] = av;
            float4 wv = *(const float4*)(W + (size_t)(k0 + r) * N + n0 + c4);
            *(float4*)&Ws[r][c4] = wv;
        }
        __syncthreads();
#pragma unroll 8
        for (int kk = 0; kk < 64; ++kk) {
            float a0 = As[ty * 4 + 0][kk];
            float a1 = As[ty * 4 + 1][kk];
            float a2 = As[ty * 4 + 2][kk];
            float a3 = As[ty * 4 + 3][kk];
            float4 b = *(const float4*)&Ws[kk][tx * 4];
            acc[0][0] += a0 * b.x; acc[0][1] += a0 * b.y; acc[0][2] += a0 * b.z; acc[0][3] += a0 * b.w;
            acc[1][0] += a1 * b.x; acc[1][1] += a1 * b.y; acc[1][2] += a1 * b.z; acc[1][3] += a1 * b.w;
            acc[2][0] += a2 * b.x; acc[2][1] += a2 * b.y; acc[2][2] += a2 * b.z; acc[2][3] += a2 * b.w;
            acc[3][0] += a3 * b.x; acc[3][1] += a3 * b.y; acc[3][2] += a3 * b.z; acc[3][3] += a3 * b.w;
        }
        __syncthreads();
    }

    float4 bv = *(const float4*)(bias + n0 + tx * 4);
#pragma unroll
    for (int i = 0; i < 4; ++i) {
        int gr = m0 + ty * 4 + i;
        if (gr < M) {
            float4 o;
            o.x = acc[i][0] + bv.x;
            o.y = acc[i][1] + bv.y;
            o.z = acc[i][2] + bv.z;
            o.w = acc[i][3] + bv.w;
            if (RELU) {
                o.x = fmaxf(o.x, 0.f); o.y = fmaxf(o.y, 0.f);
                o.z = fmaxf(o.z, 0.f); o.w = fmaxf(o.w, 0.f);
            }
            *(float4*)(C + (size_t)gr * N + n0 + tx * 4) = o;
        }
    }
}

// ---------------- layer2+pool, feature-chunked + XCD-pinned ----------------
// pooled[g][c0+f] += sum over graph-g contiguous edges of w * h1[src][c0+f]
// grid = NG*8 per launch; chunk = cbase + (blk&7) -> 3.2 MB h1 slice per XCD.

__global__ __launch_bounds__(256) void k_pool(
        const float* __restrict__ h1, const int* __restrict__ row_ptr,
        const int* __restrict__ gstart, const uint32_t* __restrict__ eP,
        float* __restrict__ pooled, int cbase) {
    const int g     = blockIdx.x >> 3;
    const int chunk = cbase + (blockIdx.x & 7);
    const int c0    = chunk * 16;
    const int f     = threadIdx.x & 15;
    const int grp   = threadIdx.x >> 4;  // 0..15
    const int e0 = row_ptr[gstart[g]];
    const int e1 = row_ptr[gstart[g + 1]];

    float acc = 0.f;
    for (int j = e0 + grp; j < e1; j += 16) {
        uint32_t v = __builtin_nontemporal_load(eP + j);
        int s; float w;
        unpack_sw(v, s, w);
        acc += w * h1[((size_t)s << 8) + c0 + f];
    }
    // sum the 4 groups within each wave (lanes differing in bits 4,5)
    acc += __shfl_xor(acc, 16);
    acc += __shfl_xor(acc, 32);
    __shared__ float red[4][16];
    int lane = threadIdx.x & 63, wv = threadIdx.x >> 6;
    if (lane < 16) red[wv][lane] = acc;
    __syncthreads();
    if (threadIdx.x < 16) {
        float v = red[0][threadIdx.x] + red[1][threadIdx.x] +
                  red[2][threadIdx.x] + red[3][threadIdx.x];
        atomicAdd(&pooled[g * HID + c0 + threadIdx.x], v);
    }
}

// ---------------- emb = pooled @ W2 + b2, then heads (merged) ----------------

__global__ __launch_bounds__(128) void k_head(const float* __restrict__ pooled,
                                              const float* __restrict__ W2,
                                              const float* __restrict__ b2,
                                              const float* __restrict__ Wg,
                                              const float* __restrict__ bg,
                                              const float* __restrict__ Wf,
                                              const float* __restrict__ bf,
                                              float* __restrict__ out_emb,
                                              float* __restrict__ out_gl,
                                              float* __restrict__ out_fl) {
    __shared__ float p[HID];
    __shared__ float e[EMB];
    __shared__ float gl[NGRP];
    __shared__ int ps;
    int g = blockIdx.x, c = threadIdx.x;
    for (int i = c; i < HID; i += 128) p[i] = pooled[(size_t)g * HID + i];
    __syncthreads();
    float a = b2[c];
    for (int k = 0; k < HID; ++k) a += p[k] * W2[(size_t)k * EMB + c];
    e[c] = a;
    out_emb[(size_t)g * EMB + c] = a;
    __syncthreads();
    if (c < NGRP) {
        float s = bg[c];
        for (int d = 0; d < EMB; ++d) s += e[d] * Wg[d * NGRP + c];
        gl[c] = s;
        out_gl[g * NGRP + c] = s;
    }
    __syncthreads();
    if (c == 0) {
        int bi = 0;
        float bv = gl[0];
        for (int t2 = 1; t2 < NGRP; ++t2)
            if (gl[t2] > bv) { bv = gl[t2]; bi = t2; }
        ps = bi;
    }
    __syncthreads();
    int pr = ps;
    float s = bf[pr * NFAM + c];
    for (int d = 0; d < EMB; ++d) s += e[d] * Wf[((size_t)pr * EMB + d) * NFAM + c];
    out_fl[g * NFAM + c] = s;
}

// ---------------- launch ----------------

extern "C" void kernel_launch(void* const* d_in, const int* in_sizes, int n_in,
                              void* d_out, int out_size, void* d_ws, size_t ws_size,
                              hipStream_t stream) {
    const float* x   = (const float*)d_in[0];
    const int*   ei  = (const int*)d_in[1];
    const int*   bat = (const int*)d_in[2];
    const float* W1  = (const float*)d_in[3];
    const float* b1  = (const float*)d_in[4];
    const float* W2  = (const float*)d_in[5];
    const float* b2  = (const float*)d_in[6];
    const float* Wg  = (const float*)d_in[7];
    const float* bg  = (const float*)d_in[8];
    const float* Wf  = (const float*)d_in[9];
    const float* bf  = (const float*)d_in[10];

    float* out     = (float*)d_out;
    float* out_emb = out;                        // 256*128
    float* out_gl  = out + (size_t)NG * EMB;     // 256*16
    float* out_fl  = out_gl + (size_t)NG * NGRP; // 256*128

    char* w = (char*)d_ws;
    auto alloc = [&](size_t bytes) {
        char* p = w;
        w += (bytes + 255) & ~(size_t)255;
        return p;
    };
    int*      degi    = (int*)alloc((size_t)NN * 4);
    float*    dinv    = (float*)alloc((size_t)NN * 4);
    int*      row_ptr = (int*)alloc((size_t)(NN + 1) * 4);
    int*      cursor  = (int*)alloc((size_t)NN * 4);
    uint32_t* eA      = (uint32_t*)alloc((size_t)NETOT * 4);
    uint32_t* eP      = (uint32_t*)alloc((size_t)NETOT * 4);
    int*      gstart  = (int*)alloc((size_t)(NG + 1) * 4);
    float*    rcnt    = (float*)alloc((size_t)NG * 4);
    float*    xa      = (float*)alloc((size_t)NN * FIN * 4);
    float*    h1      = (float*)alloc((size_t)NN * HID * 4);
    float*    pooled  = (float*)alloc((size_t)NG * HID * 4);

    const int* esrc = ei;
    const int* edst = ei + NE;

    // graph structure
    k_init_deg<<<(NN + 255) / 256, 256, 0, stream>>>(degi, NN);
    k_count<<<(NE + 255) / 256, 256, 0, stream>>>(edst, degi, NE);
    {
        int nthr = NG * HID;  // 65536 >= NN
        k_prep<<<(nthr + 255) / 256, 256, 0, stream>>>(degi, bat, dinv, gstart, pooled, NN, NG);
    }
    k_scan<<<1, 1024, 0, stream>>>(degi, gstart, rcnt, row_ptr, cursor, NN);
    k_build<<<(NETOT + 255) / 256, 256, 0, stream>>>(esrc, edst, bat, dinv, rcnt, row_ptr,
                                                     cursor, eA, eP, NN, NE);

    // layer 1: xa = S x (chunked, XCD-pinned), then h1 = relu(xa @ W1 + b1)
    {
        int nodeBlocks = (NN + 63) / 64;
        k_agg<<<nodeBlocks * 8, 256, 0, stream>>>(x, row_ptr, eA, dinv, xa, NN);
        dim3 grid((NN + 63) / 64, HID / 64);
        k_gemm_bias<true><<<grid, 256, 0, stream>>>(xa, W1, b1, h1, NN, HID, FIN);
    }

    // layer 2 + pool (chunked, XCD-pinned, two launches of 8 chunks each)
    k_pool<<<NG * 8, 256, 0, stream>>>(h1, row_ptr, gstart, eP, pooled, 0);
    k_pool<<<NG * 8, 256, 0, stream>>>(h1, row_ptr, gstart, eP, pooled, 8);

    // emb + heads
    k_head<<<NG, 128, 0, stream>>>(pooled, W2, b2, Wg, bg, Wf, bf,
                                   out_emb, out_gl, out_fl);
}

// Round 5
// 466.656 us; speedup vs baseline: 2.0779x; 2.0779x over previous
//
#include <hip/hip_runtime.h>
#include <cstddef>
#include <cstdint>

static constexpr int NN   = 50000;   // nodes
static constexpr int NE   = 800000;  // edges (without self loops)
static constexpr int NG   = 256;     // graphs
static constexpr int FIN  = 128;
static constexpr int HID  = 256;
static constexpr int EMB  = 128;
static constexpr int NGRP = 16;
static constexpr int NFAM = 128;
static constexpr int NETOT = NE + NN;  // edges + self loops

using bf16x8 = __attribute__((ext_vector_type(8))) short;
using f32x4  = __attribute__((ext_vector_type(4))) float;

// fp32 -> bf16 (RNE) and back, bit-level (values are finite)
__device__ __forceinline__ unsigned short f2bf(float f) {
    uint32_t u = __float_as_uint(f);
    u += 0x7FFFu + ((u >> 16) & 1u);
    return (unsigned short)(u >> 16);
}
__device__ __forceinline__ float bf2f(unsigned short u) {
    return __uint_as_float((uint32_t)u << 16);
}

// ---------------- setup ----------------

__global__ void k_init_deg(int* __restrict__ degi, int n) {
    int i = blockIdx.x * blockDim.x + threadIdx.x;
    if (i < n) degi[i] = 1;  // self loop
}

__global__ void k_count(const int* __restrict__ edst, int* __restrict__ degi, int e) {
    int i = blockIdx.x * blockDim.x + threadIdx.x;
    if (i < e) atomicAdd(degi + edst[i], 1);
}

// dinv + gstart + zero(pooled) + x->bf16 conversion (grid-stride)
__global__ void k_prep(const int* __restrict__ degi, const int* __restrict__ batch,
                       const float* __restrict__ x, unsigned short* __restrict__ xb,
                       float* __restrict__ dinv, int* __restrict__ gstart,
                       float* __restrict__ pooled, int n, int G) {
    int i = blockIdx.x * blockDim.x + threadIdx.x;   // 0..65535
    if (i < NG * HID) pooled[i] = 0.f;
    for (size_t j = i; j < (size_t)NN * FIN; j += (size_t)NG * HID)
        xb[j] = f2bf(x[j]);
    if (i >= n) return;
    dinv[i] = rsqrtf((float)degi[i]);
    int b  = batch[i];
    int pb = (i == 0) ? -1 : batch[i - 1];
    for (int g = pb + 1; g <= b; ++g) gstart[g] = i;
    if (i == n - 1) {
        for (int g = b + 1; g <= G; ++g) gstart[g] = n;
    }
}

// W1 [128][256] fp32 -> W1t [256][128] bf16
__global__ void k_w1t(const float* __restrict__ W1, unsigned short* __restrict__ W1t) {
    int t = blockIdx.x * blockDim.x + threadIdx.x;  // 0..32767
    int nidx = t >> 7, k = t & 127;
    W1t[t] = f2bf(W1[(size_t)k * HID + nidx]);
}

// rcnt + exclusive scan of degi -> row_ptr; cursor init 1 (slot 0 = self loop)
__global__ __launch_bounds__(1024) void k_scan(const int* __restrict__ degi,
                                               const int* __restrict__ gstart,
                                               float* __restrict__ rcnt,
                                               int* __restrict__ row_ptr,
                                               int* __restrict__ cursor, int n) {
    const int t = threadIdx.x;
    if (t < NG) {
        int c = gstart[t + 1] - gstart[t];
        rcnt[t] = 1.0f / (float)max(c, 1);
    }
    __shared__ int ps[1024];
    const int CH = (n + 1023) / 1024;
    int lo = t * CH;
    int hi = min(lo + CH, n);
    int s = 0;
    for (int i = lo; i < hi; ++i) s += degi[i];
    ps[t] = s;
    __syncthreads();
    for (int off = 1; off < 1024; off <<= 1) {
        int v = (t >= off) ? ps[t - off] : 0;
        __syncthreads();
        if (t >= off) ps[t] += v;
        __syncthreads();
    }
    int run = (t == 0) ? 0 : ps[t - 1];
    for (int i = lo; i < hi; ++i) {
        row_ptr[i] = run;
        cursor[i]  = 1;
        run += degi[i];
    }
    if (t == 1023) row_ptr[n] = ps[1023];
}

// CSR fill: self loops (slot 0) + edges; col + fp32 pool weight
__global__ void k_build(const int* __restrict__ esrc, const int* __restrict__ edst,
                        const int* __restrict__ batch, const float* __restrict__ dinv,
                        const float* __restrict__ rcnt, const int* __restrict__ row_ptr,
                        int* __restrict__ cursor, int* __restrict__ col,
                        float* __restrict__ wP, int n, int e) {
    int i = blockIdx.x * blockDim.x + threadIdx.x;
    if (i < n) {
        int p = row_ptr[i];
        float di = dinv[i];
        col[p] = i;
        wP[p]  = di * di * rcnt[batch[i]];
    } else if (i < n + e) {
        int ei = i - n;
        int d = edst[ei], s = esrc[ei];
        int p = atomicAdd(cursor + d, 1);
        int idx = row_ptr[d] + p;
        col[idx] = s;
        wP[idx]  = dinv[d] * dinv[s] * rcnt[batch[d]];
    }
}

// ---------------- layer-1 gather: xa[i] = bf16( dinv_i * sum_j dinv[col]*xb[col] ) ----
// wave per node, 64 lanes x uint (2 bf16) = 256 B/row.

__global__ __launch_bounds__(256) void k_agg(
        const unsigned short* __restrict__ xb, const int* __restrict__ row_ptr,
        const int* __restrict__ col, const float* __restrict__ dinv,
        unsigned short* __restrict__ xa, int n) {
    int node = blockIdx.x * 4 + (threadIdx.x >> 6);
    if (node >= n) return;
    int lane = threadIdx.x & 63;
    float a0 = 0.f, a1 = 0.f;
    int beg = row_ptr[node], end = row_ptr[node + 1];
    for (int j = beg; j < end; ++j) {
        int s = __builtin_nontemporal_load(col + j);
        float ds = dinv[s];
        uint32_t v = *(const uint32_t*)(xb + ((size_t)s << 7) + lane * 2);
        a0 += ds * bf2f((unsigned short)(v & 0xFFFFu));
        a1 += ds * bf2f((unsigned short)(v >> 16));
    }
    float di = dinv[node];
    uint32_t o = (uint32_t)f2bf(di * a0) | ((uint32_t)f2bf(di * a1) << 16);
    *(uint32_t*)(xa + ((size_t)node << 7) + lane * 2) = o;
}

// ---------------- MFMA GEMM: h1 = bf16(relu(xa @ W1 + b1)) ----------------
// A = xa bf16 [M,128] row-major; Bt = W1t bf16 [256,128] row-major.
// block 256 = 4 waves; tile 64(M) x 64(N); wave w -> cols n0+w*16; K=128 in 4 steps.

__global__ __launch_bounds__(256) void k_gemm_mfma(
        const unsigned short* __restrict__ A, const unsigned short* __restrict__ Bt,
        const float* __restrict__ bias, unsigned short* __restrict__ C, int M) {
    const int m0 = blockIdx.x * 64;
    const int w  = threadIdx.x >> 6;
    const int l  = threadIdx.x & 63;
    const int lr = l & 15;
    const int lk = l >> 4;  // 0..3
    const int n0 = blockIdx.y * 64 + w * 16;

    f32x4 acc[4] = {};
#pragma unroll
    for (int ks = 0; ks < 4; ++ks) {
        const int k0 = ks * 32;
        bf16x8 bfr = *(const bf16x8*)(Bt + (size_t)(n0 + lr) * FIN + k0 + lk * 8);
#pragma unroll
        for (int mi = 0; mi < 4; ++mi) {
            int row = m0 + mi * 16 + lr;
            row = min(row, M - 1);  // clamp; OOB rows guarded at write
            bf16x8 afr = *(const bf16x8*)(A + ((size_t)row << 7) + k0 + lk * 8);
            acc[mi] = __builtin_amdgcn_mfma_f32_16x16x32_bf16(afr, bfr, acc[mi], 0, 0, 0);
        }
    }
    float b = bias[n0 + lr];
#pragma unroll
    for (int mi = 0; mi < 4; ++mi) {
#pragma unroll
        for (int r = 0; r < 4; ++r) {
            int row = m0 + mi * 16 + lk * 4 + r;
            if (row < M) {
                float v = fmaxf(acc[mi][r] + b, 0.f);
                C[(size_t)row * HID + n0 + lr] = f2bf(v);
            }
        }
    }
}

// ---------------- layer2+pool: pooled[g] += sum over graph-contiguous edges ----
// 8 blocks/graph; wave reads full 256-bf16 row (512 B); LDS reduce; 256 atomics/block.

__global__ __launch_bounds__(256) void k_pool(
        const unsigned short* __restrict__ h1, const int* __restrict__ row_ptr,
        const int* __restrict__ gstart, const int* __restrict__ col,
        const float* __restrict__ wP, float* __restrict__ pooled) {
    __shared__ float red[4][HID];
    const int g  = blockIdx.x >> 3;
    const int k  = blockIdx.x & 7;
    const int e0 = row_ptr[gstart[g]];
    const int e1 = row_ptr[gstart[g + 1]];
    const int len = e1 - e0;
    const int per = (len + 7) >> 3;
    const int s0  = e0 + k * per;
    const int s1  = min(s0 + per, e1);
    const int lane = threadIdx.x & 63;
    const int wv   = threadIdx.x >> 6;

    float4 acc = make_float4(0.f, 0.f, 0.f, 0.f);
    for (int j = s0 + wv; j < s1; j += 4) {
        int s   = __builtin_nontemporal_load(col + j);
        float w = __builtin_nontemporal_load(wP + j);
        ushort4 v = *(const ushort4*)(h1 + (size_t)s * HID + lane * 4);
        acc.x += w * bf2f(v.x);
        acc.y += w * bf2f(v.y);
        acc.z += w * bf2f(v.z);
        acc.w += w * bf2f(v.w);
    }
    *(float4*)&red[wv][lane * 4] = acc;
    __syncthreads();
    int t = threadIdx.x;  // 0..255 covers HID floats
    float v = red[0][t] + red[1][t] + red[2][t] + red[3][t];
    if (v != 0.f) atomicAdd(&pooled[g * HID + t], v);
}

// ---------------- emb = pooled @ W2 + b2, then heads (merged, fp32) ----------------

__global__ __launch_bounds__(128) void k_head(const float* __restrict__ pooled,
                                              const float* __restrict__ W2,
                                              const float* __restrict__ b2,
                                              const float* __restrict__ Wg,
                                              const float* __restrict__ bg,
                                              const float* __restrict__ Wf,
                                              const float* __restrict__ bf,
                                              float* __restrict__ out_emb,
                                              float* __restrict__ out_gl,
                                              float* __restrict__ out_fl) {
    __shared__ float p[HID];
    __shared__ float e[EMB];
    __shared__ float gl[NGRP];
    __shared__ int ps;
    int g = blockIdx.x, c = threadIdx.x;
    for (int i = c; i < HID; i += 128) p[i] = pooled[(size_t)g * HID + i];
    __syncthreads();
    float a = b2[c];
    for (int k = 0; k < HID; ++k) a += p[k] * W2[(size_t)k * EMB + c];
    e[c] = a;
    out_emb[(size_t)g * EMB + c] = a;
    __syncthreads();
    if (c < NGRP) {
        float s = bg[c];
        for (int d = 0; d < EMB; ++d) s += e[d] * Wg[d * NGRP + c];
        gl[c] = s;
        out_gl[g * NGRP + c] = s;
    }
    __syncthreads();
    if (c == 0) {
        int bi = 0;
        float bv = gl[0];
        for (int t2 = 1; t2 < NGRP; ++t2)
            if (gl[t2] > bv) { bv = gl[t2]; bi = t2; }
        ps = bi;
    }
    __syncthreads();
    int pr = ps;
    float s = bf[pr * NFAM + c];
    for (int d = 0; d < EMB; ++d) s += e[d] * Wf[((size_t)pr * EMB + d) * NFAM + c];
    out_fl[g * NFAM + c] = s;
}

// ---------------- launch ----------------

extern "C" void kernel_launch(void* const* d_in, const int* in_sizes, int n_in,
                              void* d_out, int out_size, void* d_ws, size_t ws_size,
                              hipStream_t stream) {
    const float* x   = (const float*)d_in[0];
    const int*   ei  = (const int*)d_in[1];
    const int*   bat = (const int*)d_in[2];
    const float* W1  = (const float*)d_in[3];
    const float* b1  = (const float*)d_in[4];
    const float* W2  = (const float*)d_in[5];
    const float* b2  = (const float*)d_in[6];
    const float* Wg  = (const float*)d_in[7];
    const float* bg  = (const float*)d_in[8];
    const float* Wf  = (const float*)d_in[9];
    const float* bf  = (const float*)d_in[10];

    float* out     = (float*)d_out;
    float* out_emb = out;                        // 256*128
    float* out_gl  = out + (size_t)NG * EMB;     // 256*16
    float* out_fl  = out_gl + (size_t)NG * NGRP; // 256*128

    char* w = (char*)d_ws;
    auto alloc = [&](size_t bytes) {
        char* p = w;
        w += (bytes + 255) & ~(size_t)255;
        return p;
    };
    int*            degi    = (int*)alloc((size_t)NN * 4);
    float*          dinv    = (float*)alloc((size_t)NN * 4);
    int*            row_ptr = (int*)alloc((size_t)(NN + 1) * 4);
    int*            cursor  = (int*)alloc((size_t)NN * 4);
    int*            col     = (int*)alloc((size_t)NETOT * 4);
    float*          wP      = (float*)alloc((size_t)NETOT * 4);
    int*            gstart  = (int*)alloc((size_t)(NG + 1) * 4);
    float*          rcnt    = (float*)alloc((size_t)NG * 4);
    unsigned short* xb      = (unsigned short*)alloc((size_t)NN * FIN * 2);
    unsigned short* xa      = (unsigned short*)alloc((size_t)NN * FIN * 2);
    unsigned short* W1t     = (unsigned short*)alloc((size_t)HID * FIN * 2);
    unsigned short* h1      = (unsigned short*)alloc((size_t)NN * HID * 2);
    float*          pooled  = (float*)alloc((size_t)NG * HID * 4);

    const int* esrc = ei;
    const int* edst = ei + NE;

    // graph structure + conversions
    k_init_deg<<<(NN + 255) / 256, 256, 0, stream>>>(degi, NN);
    k_count<<<(NE + 255) / 256, 256, 0, stream>>>(edst, degi, NE);
    k_prep<<<(NG * HID + 255) / 256, 256, 0, stream>>>(degi, bat, x, xb, dinv, gstart,
                                                       pooled, NN, NG);
    k_w1t<<<(HID * FIN + 255) / 256, 256, 0, stream>>>(W1, W1t);
    k_scan<<<1, 1024, 0, stream>>>(degi, gstart, rcnt, row_ptr, cursor, NN);
    k_build<<<(NETOT + 255) / 256, 256, 0, stream>>>(esrc, edst, bat, dinv, rcnt,
                                                     row_ptr, cursor, col, wP, NN, NE);

    // layer 1: xa = bf16(S xb), h1 = bf16(relu(xa @ W1 + b1)) via MFMA
    k_agg<<<(NN + 3) / 4, 256, 0, stream>>>(xb, row_ptr, col, dinv, xa, NN);
    {
        dim3 grid((NN + 63) / 64, HID / 64);
        k_gemm_mfma<<<grid, 256, 0, stream>>>(xa, W1t, b1, h1, NN);
    }

    // layer 2 + pool
    k_pool<<<NG * 8, 256, 0, stream>>>(h1, row_ptr, gstart, col, wP, pooled);

    // emb + heads
    k_head<<<NG, 128, 0, stream>>>(pooled, W2, b2, Wg, bg, Wf, bf,
                                   out_emb, out_gl, out_fl);
}

// Round 6
// 365.178 us; speedup vs baseline: 2.6553x; 1.2779x over previous
//
#include <hip/hip_runtime.h>
#include <cstddef>
#include <cstdint>

static constexpr int NN   = 50000;   // nodes
static constexpr int NE   = 800000;  // edges (without self loops)
static constexpr int NG   = 256;     // graphs
static constexpr int FIN  = 128;
static constexpr int HID  = 256;
static constexpr int EMB  = 128;
static constexpr int NGRP = 16;
static constexpr int NFAM = 128;
static constexpr int NETOT = NE + NN;  // edges + self loops

static constexpr int SCAN_B  = 256;                       // scan blocks
static constexpr int SCAN_CH = (NN + SCAN_B - 1) / SCAN_B;  // 196 elems/block (<=256)

using bf16x8 = __attribute__((ext_vector_type(8))) short;
using f32x4  = __attribute__((ext_vector_type(4))) float;

// fp32 -> bf16 (RNE) and back, bit-level (values are finite)
__device__ __forceinline__ unsigned short f2bf(float f) {
    uint32_t u = __float_as_uint(f);
    u += 0x7FFFu + ((u >> 16) & 1u);
    return (unsigned short)(u >> 16);
}
__device__ __forceinline__ float bf2f(unsigned short u) {
    return __uint_as_float((uint32_t)u << 16);
}

// ---------------- setup ----------------

__global__ void k_init_deg(int* __restrict__ degi, int n) {
    int i = blockIdx.x * blockDim.x + threadIdx.x;
    if (i < n) degi[i] = 1;  // self loop
}

__global__ void k_count(const int* __restrict__ edst, int* __restrict__ degi, int e) {
    int i = blockIdx.x * blockDim.x + threadIdx.x;
    if (i < e) atomicAdd(degi + edst[i], 1);
}

// dinv + gstart + zero(pooled) + x->bf16 conversion (grid-stride)
__global__ void k_prep(const int* __restrict__ degi, const int* __restrict__ batch,
                       const float* __restrict__ x, unsigned short* __restrict__ xb,
                       float* __restrict__ dinv, int* __restrict__ gstart,
                       float* __restrict__ pooled, int n, int G) {
    int i = blockIdx.x * blockDim.x + threadIdx.x;   // 0..65535
    if (i < NG * HID) pooled[i] = 0.f;
    for (size_t j = i; j < (size_t)NN * FIN; j += (size_t)NG * HID)
        xb[j] = f2bf(x[j]);
    if (i >= n) return;
    dinv[i] = rsqrtf((float)degi[i]);
    int b  = batch[i];
    int pb = (i == 0) ? -1 : batch[i - 1];
    for (int g = pb + 1; g <= b; ++g) gstart[g] = i;
    if (i == n - 1) {
        for (int g = b + 1; g <= G; ++g) gstart[g] = n;
    }
}

// W1 [128][256] fp32 -> W1t [256][128] bf16
__global__ void k_w1t(const float* __restrict__ W1, unsigned short* __restrict__ W1t) {
    int t = blockIdx.x * blockDim.x + threadIdx.x;  // 0..32767
    int nidx = t >> 7, k = t & 127;
    W1t[t] = f2bf(W1[(size_t)k * HID + nidx]);
}

// ---------------- parallel scan (2 kernels) ----------------
// scanA: per-block inclusive LDS scan of degi chunk; row_ptr <- local exclusive
//        prefix; bsum[b] <- block total.
__global__ __launch_bounds__(256) void k_scanA(const int* __restrict__ degi,
                                               int* __restrict__ row_ptr,
                                               int* __restrict__ bsum, int n) {
    __shared__ int sh[256];
    const int b = blockIdx.x, t = threadIdx.x;
    const int idx = b * SCAN_CH + t;
    int v = 0;
    if (t < SCAN_CH && idx < n) v = degi[idx];
    sh[t] = v;
    __syncthreads();
    for (int off = 1; off < 256; off <<= 1) {
        int y = (t >= off) ? sh[t - off] : 0;
        __syncthreads();
        if (t >= off) sh[t] += y;
        __syncthreads();
    }
    if (t < SCAN_CH && idx < n) row_ptr[idx] = sh[t] - v;  // exclusive
    if (t == 255) bsum[b] = sh[255];
}

// scanB: each block scans bsum in LDS, adds its offset to row_ptr chunk, inits
//        cursor=1; block 0 writes row_ptr[n] and rcnt.
__global__ __launch_bounds__(256) void k_scanB(const int* __restrict__ bsum,
                                               const int* __restrict__ gstart,
                                               float* __restrict__ rcnt,
                                               int* __restrict__ row_ptr,
                                               int* __restrict__ cursor, int n) {
    __shared__ int sh[SCAN_B];
    const int b = blockIdx.x, t = threadIdx.x;
    sh[t] = bsum[t];
    __syncthreads();
    for (int off = 1; off < SCAN_B; off <<= 1) {
        int y = (t >= off) ? sh[t - off] : 0;
        __syncthreads();
        if (t >= off) sh[t] += y;
        __syncthreads();
    }
    const int boff = (b == 0) ? 0 : sh[b - 1];
    const int idx  = b * SCAN_CH + t;
    if (t < SCAN_CH && idx < n) {
        row_ptr[idx] += boff;
        cursor[idx] = 1;
    }
    if (b == 0 && t == 0) row_ptr[n] = sh[SCAN_B - 1];
    if (b == 0 && t < NG) {
        int c = gstart[t + 1] - gstart[t];
        rcnt[t] = 1.0f / (float)max(c, 1);
    }
}

// CSR fill: self loops (slot 0) + edges; col + fp32 pool weight
__global__ void k_build(const int* __restrict__ esrc, const int* __restrict__ edst,
                        const int* __restrict__ batch, const float* __restrict__ dinv,
                        const float* __restrict__ rcnt, const int* __restrict__ row_ptr,
                        int* __restrict__ cursor, int* __restrict__ col,
                        float* __restrict__ wP, int n, int e) {
    int i = blockIdx.x * blockDim.x + threadIdx.x;
    if (i < n) {
        int p = row_ptr[i];
        float di = dinv[i];
        col[p] = i;
        wP[p]  = di * di * rcnt[batch[i]];
    } else if (i < n + e) {
        int ei = i - n;
        int d = edst[ei], s = esrc[ei];
        int p = atomicAdd(cursor + d, 1);
        int idx = row_ptr[d] + p;
        col[idx] = s;
        wP[idx]  = dinv[d] * dinv[s] * rcnt[batch[d]];
    }
}

// ---------------- layer-1 gather: xa[i] = bf16( dinv_i * sum_j dinv[col]*xb[col] ) ----
// wave per node, 64 lanes x uint (2 bf16) = 256 B/row.

__global__ __launch_bounds__(256) void k_agg(
        const unsigned short* __restrict__ xb, const int* __restrict__ row_ptr,
        const int* __restrict__ col, const float* __restrict__ dinv,
        unsigned short* __restrict__ xa, int n) {
    int node = blockIdx.x * 4 + (threadIdx.x >> 6);
    if (node >= n) return;
    int lane = threadIdx.x & 63;
    float a0 = 0.f, a1 = 0.f;
    int beg = row_ptr[node], end = row_ptr[node + 1];
    for (int j = beg; j < end; ++j) {
        int s = __builtin_nontemporal_load(col + j);
        float ds = dinv[s];
        uint32_t v = *(const uint32_t*)(xb + ((size_t)s << 7) + lane * 2);
        a0 += ds * bf2f((unsigned short)(v & 0xFFFFu));
        a1 += ds * bf2f((unsigned short)(v >> 16));
    }
    float di = dinv[node];
    uint32_t o = (uint32_t)f2bf(di * a0) | ((uint32_t)f2bf(di * a1) << 16);
    *(uint32_t*)(xa + ((size_t)node << 7) + lane * 2) = o;
}

// ---------------- MFMA GEMM: h1 = bf16(relu(xa @ W1 + b1)) ----------------
// A = xa bf16 [M,128] row-major; Bt = W1t bf16 [256,128] row-major.
// block 256 = 4 waves; tile 64(M) x 64(N); wave w -> cols n0+w*16; K=128 in 4 steps.

__global__ __launch_bounds__(256) void k_gemm_mfma(
        const unsigned short* __restrict__ A, const unsigned short* __restrict__ Bt,
        const float* __restrict__ bias, unsigned short* __restrict__ C, int M) {
    const int m0 = blockIdx.x * 64;
    const int w  = threadIdx.x >> 6;
    const int l  = threadIdx.x & 63;
    const int lr = l & 15;
    const int lk = l >> 4;  // 0..3
    const int n0 = blockIdx.y * 64 + w * 16;

    f32x4 acc[4] = {};
#pragma unroll
    for (int ks = 0; ks < 4; ++ks) {
        const int k0 = ks * 32;
        bf16x8 bfr = *(const bf16x8*)(Bt + (size_t)(n0 + lr) * FIN + k0 + lk * 8);
#pragma unroll
        for (int mi = 0; mi < 4; ++mi) {
            int row = m0 + mi * 16 + lr;
            row = min(row, M - 1);  // clamp; OOB rows guarded at write
            bf16x8 afr = *(const bf16x8*)(A + ((size_t)row << 7) + k0 + lk * 8);
            acc[mi] = __builtin_amdgcn_mfma_f32_16x16x32_bf16(afr, bfr, acc[mi], 0, 0, 0);
        }
    }
    float b = bias[n0 + lr];
#pragma unroll
    for (int mi = 0; mi < 4; ++mi) {
#pragma unroll
        for (int r = 0; r < 4; ++r) {
            int row = m0 + mi * 16 + lk * 4 + r;
            if (row < M) {
                float v = fmaxf(acc[mi][r] + b, 0.f);
                C[(size_t)row * HID + n0 + lr] = f2bf(v);
            }
        }
    }
}

// ---------------- layer2+pool: pooled[g] += sum over graph-contiguous edges ----
// 8 blocks/graph; wave reads full 256-bf16 row (512 B); LDS reduce; 256 atomics/block.

__global__ __launch_bounds__(256) void k_pool(
        const unsigned short* __restrict__ h1, const int* __restrict__ row_ptr,
        const int* __restrict__ gstart, const int* __restrict__ col,
        const float* __restrict__ wP, float* __restrict__ pooled) {
    __shared__ float red[4][HID];
    const int g  = blockIdx.x >> 3;
    const int k  = blockIdx.x & 7;
    const int e0 = row_ptr[gstart[g]];
    const int e1 = row_ptr[gstart[g + 1]];
    const int len = e1 - e0;
    const int per = (len + 7) >> 3;
    const int s0  = e0 + k * per;
    const int s1  = min(s0 + per, e1);
    const int lane = threadIdx.x & 63;
    const int wv   = threadIdx.x >> 6;

    float4 acc = make_float4(0.f, 0.f, 0.f, 0.f);
    for (int j = s0 + wv; j < s1; j += 4) {
        int s   = __builtin_nontemporal_load(col + j);
        float w = __builtin_nontemporal_load(wP + j);
        ushort4 v = *(const ushort4*)(h1 + (size_t)s * HID + lane * 4);
        acc.x += w * bf2f(v.x);
        acc.y += w * bf2f(v.y);
        acc.z += w * bf2f(v.z);
        acc.w += w * bf2f(v.w);
    }
    *(float4*)&red[wv][lane * 4] = acc;
    __syncthreads();
    int t = threadIdx.x;  // 0..255 covers HID floats
    float v = red[0][t] + red[1][t] + red[2][t] + red[3][t];
    if (v != 0.f) atomicAdd(&pooled[g * HID + t], v);
}

// ---------------- emb = pooled @ W2 + b2, then heads (merged, fp32) ----------------

__global__ __launch_bounds__(128) void k_head(const float* __restrict__ pooled,
                                              const float* __restrict__ W2,
                                              const float* __restrict__ b2,
                                              const float* __restrict__ Wg,
                                              const float* __restrict__ bg,
                                              const float* __restrict__ Wf,
                                              const float* __restrict__ bf,
                                              float* __restrict__ out_emb,
                                              float* __restrict__ out_gl,
                                              float* __restrict__ out_fl) {
    __shared__ float p[HID];
    __shared__ float e[EMB];
    __shared__ float gl[NGRP];
    __shared__ int ps;
    int g = blockIdx.x, c = threadIdx.x;
    for (int i = c; i < HID; i += 128) p[i] = pooled[(size_t)g * HID + i];
    __syncthreads();
    float a = b2[c];
    for (int k = 0; k < HID; ++k) a += p[k] * W2[(size_t)k * EMB + c];
    e[c] = a;
    out_emb[(size_t)g * EMB + c] = a;
    __syncthreads();
    if (c < NGRP) {
        float s = bg[c];
        for (int d = 0; d < EMB; ++d) s += e[d] * Wg[d * NGRP + c];
        gl[c] = s;
        out_gl[g * NGRP + c] = s;
    }
    __syncthreads();
    if (c == 0) {
        int bi = 0;
        float bv = gl[0];
        for (int t2 = 1; t2 < NGRP; ++t2)
            if (gl[t2] > bv) { bv = gl[t2]; bi = t2; }
        ps = bi;
    }
    __syncthreads();
    int pr = ps;
    float s = bf[pr * NFAM + c];
    for (int d = 0; d < EMB; ++d) s += e[d] * Wf[((size_t)pr * EMB + d) * NFAM + c];
    out_fl[g * NFAM + c] = s;
}

// ---------------- launch ----------------

extern "C" void kernel_launch(void* const* d_in, const int* in_sizes, int n_in,
                              void* d_out, int out_size, void* d_ws, size_t ws_size,
                              hipStream_t stream) {
    const float* x   = (const float*)d_in[0];
    const int*   ei  = (const int*)d_in[1];
    const int*   bat = (const int*)d_in[2];
    const float* W1  = (const float*)d_in[3];
    const float* b1  = (const float*)d_in[4];
    const float* W2  = (const float*)d_in[5];
    const float* b2  = (const float*)d_in[6];
    const float* Wg  = (const float*)d_in[7];
    const float* bg  = (const float*)d_in[8];
    const float* Wf  = (const float*)d_in[9];
    const float* bf  = (const float*)d_in[10];

    float* out     = (float*)d_out;
    float* out_emb = out;                        // 256*128
    float* out_gl  = out + (size_t)NG * EMB;     // 256*16
    float* out_fl  = out_gl + (size_t)NG * NGRP; // 256*128

    char* w = (char*)d_ws;
    auto alloc = [&](size_t bytes) {
        char* p = w;
        w += (bytes + 255) & ~(size_t)255;
        return p;
    };
    int*            degi    = (int*)alloc((size_t)NN * 4);
    float*          dinv    = (float*)alloc((size_t)NN * 4);
    int*            row_ptr = (int*)alloc((size_t)(NN + 1) * 4);
    int*            cursor  = (int*)alloc((size_t)NN * 4);
    int*            bsum    = (int*)alloc((size_t)SCAN_B * 4);
    int*            col     = (int*)alloc((size_t)NETOT * 4);
    float*          wP      = (float*)alloc((size_t)NETOT * 4);
    int*            gstart  = (int*)alloc((size_t)(NG + 1) * 4);
    float*          rcnt    = (float*)alloc((size_t)NG * 4);
    unsigned short* xb      = (unsigned short*)alloc((size_t)NN * FIN * 2);
    unsigned short* xa      = (unsigned short*)alloc((size_t)NN * FIN * 2);
    unsigned short* W1t     = (unsigned short*)alloc((size_t)HID * FIN * 2);
    unsigned short* h1      = (unsigned short*)alloc((size_t)NN * HID * 2);
    float*          pooled  = (float*)alloc((size_t)NG * HID * 4);

    const int* esrc = ei;
    const int* edst = ei + NE;

    // graph structure + conversions
    k_init_deg<<<(NN + 255) / 256, 256, 0, stream>>>(degi, NN);
    k_count<<<(NE + 255) / 256, 256, 0, stream>>>(edst, degi, NE);
    k_prep<<<(NG * HID + 255) / 256, 256, 0, stream>>>(degi, bat, x, xb, dinv, gstart,
                                                       pooled, NN, NG);
    k_w1t<<<(HID * FIN + 255) / 256, 256, 0, stream>>>(W1, W1t);
    k_scanA<<<SCAN_B, 256, 0, stream>>>(degi, row_ptr, bsum, NN);
    k_scanB<<<SCAN_B, 256, 0, stream>>>(bsum, gstart, rcnt, row_ptr, cursor, NN);
    k_build<<<(NETOT + 255) / 256, 256, 0, stream>>>(esrc, edst, bat, dinv, rcnt,
                                                     row_ptr, cursor, col, wP, NN, NE);

    // layer 1: xa = bf16(S xb), h1 = bf16(relu(xa @ W1 + b1)) via MFMA
    k_agg<<<(NN + 3) / 4, 256, 0, stream>>>(xb, row_ptr, col, dinv, xa, NN);
    {
        dim3 grid((NN + 63) / 64, HID / 64);
        k_gemm_mfma<<<grid, 256, 0, stream>>>(xa, W1t, b1, h1, NN);
    }

    // layer 2 + pool
    k_pool<<<NG * 8, 256, 0, stream>>>(h1, row_ptr, gstart, col, wP, pooled);

    // emb + heads
    k_head<<<NG, 128, 0, stream>>>(pooled, W2, b2, Wg, bg, Wf, bf,
                                   out_emb, out_gl, out_fl);
}

// Round 7
// 258.553 us; speedup vs baseline: 3.7504x; 1.4124x over previous
//
#include <hip/hip_runtime.h>
#include <hip/hip_fp16.h>
#include <cstddef>
#include <cstdint>

static constexpr int NN   = 50000;   // nodes
static constexpr int NE   = 800000;  // edges (without self loops)
static constexpr int NG   = 256;     // graphs
static constexpr int FIN  = 128;
static constexpr int HID  = 256;
static constexpr int EMB  = 128;
static constexpr int NGRP = 16;
static constexpr int NFAM = 128;
static constexpr int NETOT = NE + NN;  // edges + self loops

static constexpr int SCAN_B  = 256;
static constexpr int SCAN_CH = (NN + SCAN_B - 1) / SCAN_B;  // 196

using bf16x8 = __attribute__((ext_vector_type(8))) short;
using f32x4  = __attribute__((ext_vector_type(4))) float;

__device__ __forceinline__ unsigned short f2bf(float f) {
    uint32_t u = __float_as_uint(f);
    u += 0x7FFFu + ((u >> 16) & 1u);
    return (unsigned short)(u >> 16);
}
__device__ __forceinline__ float bf2f(unsigned short u) {
    return __uint_as_float((uint32_t)u << 16);
}
// packed edge: low16 = src node, high16 = fp16 weight
__device__ __forceinline__ uint32_t pack_sw(int s, float w) {
    return (uint32_t)s | ((uint32_t)__half_as_ushort(__float2half(w)) << 16);
}
__device__ __forceinline__ void unpack_sw(uint32_t v, int& s, float& w) {
    s = (int)(v & 0xFFFFu);
    w = __half2float(__ushort_as_half((unsigned short)(v >> 16)));
}

// ---------------- setup ----------------

__global__ void k_init_deg(int* __restrict__ degi, int n) {
    int i = blockIdx.x * blockDim.x + threadIdx.x;
    if (i < n) degi[i] = 1;  // self loop
}

__global__ void k_count(const int* __restrict__ edst, int* __restrict__ degi, int e) {
    int i = blockIdx.x * blockDim.x + threadIdx.x;
    if (i < e) atomicAdd(degi + edst[i], 1);
}

// dinv + gstart + zero(pooled)
__global__ void k_prep(const int* __restrict__ degi, const int* __restrict__ batch,
                       float* __restrict__ dinv, int* __restrict__ gstart,
                       float* __restrict__ pooled, int n, int G) {
    int i = blockIdx.x * blockDim.x + threadIdx.x;   // 0..65535
    if (i < NG * HID) pooled[i] = 0.f;
    if (i >= n) return;
    dinv[i] = rsqrtf((float)degi[i]);
    int b  = batch[i];
    int pb = (i == 0) ? -1 : batch[i - 1];
    for (int g = pb + 1; g <= b; ++g) gstart[g] = i;
    if (i == n - 1) {
        for (int g = b + 1; g <= G; ++g) gstart[g] = n;
    }
}

// x -> bf16, vectorized: 8 floats -> 8 bf16 per thread
__global__ void k_xconv(const float* __restrict__ x, unsigned short* __restrict__ xb) {
    size_t i = (size_t)(blockIdx.x * blockDim.x + threadIdx.x) * 8;  // NN*FIN/8 threads
    float4 a = *(const float4*)(x + i);
    float4 b = *(const float4*)(x + i + 4);
    uint4 o;
    o.x = (uint32_t)f2bf(a.x) | ((uint32_t)f2bf(a.y) << 16);
    o.y = (uint32_t)f2bf(a.z) | ((uint32_t)f2bf(a.w) << 16);
    o.z = (uint32_t)f2bf(b.x) | ((uint32_t)f2bf(b.y) << 16);
    o.w = (uint32_t)f2bf(b.z) | ((uint32_t)f2bf(b.w) << 16);
    *(uint4*)(xb + i) = o;
}

// W1 [128][256] fp32 -> W1t [256][128] bf16
__global__ void k_w1t(const float* __restrict__ W1, unsigned short* __restrict__ W1t) {
    int t = blockIdx.x * blockDim.x + threadIdx.x;  // 0..32767
    int nidx = t >> 7, k = t & 127;
    W1t[t] = f2bf(W1[(size_t)k * HID + nidx]);
}

// ---------------- parallel scan (2 kernels) ----------------

__global__ __launch_bounds__(256) void k_scanA(const int* __restrict__ degi,
                                               int* __restrict__ row_ptr,
                                               int* __restrict__ bsum, int n) {
    __shared__ int sh[256];
    const int b = blockIdx.x, t = threadIdx.x;
    const int idx = b * SCAN_CH + t;
    int v = 0;
    if (t < SCAN_CH && idx < n) v = degi[idx];
    sh[t] = v;
    __syncthreads();
    for (int off = 1; off < 256; off <<= 1) {
        int y = (t >= off) ? sh[t - off] : 0;
        __syncthreads();
        if (t >= off) sh[t] += y;
        __syncthreads();
    }
    if (t < SCAN_CH && idx < n) row_ptr[idx] = sh[t] - v;  // exclusive
    if (t == 255) bsum[b] = sh[255];
}

__global__ __launch_bounds__(256) void k_scanB(const int* __restrict__ bsum,
                                               const int* __restrict__ gstart,
                                               float* __restrict__ rcnt,
                                               int* __restrict__ row_ptr,
                                               int* __restrict__ cursor, int n) {
    __shared__ int sh[SCAN_B];
    const int b = blockIdx.x, t = threadIdx.x;
    sh[t] = bsum[t];
    __syncthreads();
    for (int off = 1; off < SCAN_B; off <<= 1) {
        int y = (t >= off) ? sh[t - off] : 0;
        __syncthreads();
        if (t >= off) sh[t] += y;
        __syncthreads();
    }
    const int boff = (b == 0) ? 0 : sh[b - 1];
    const int idx  = b * SCAN_CH + t;
    if (t < SCAN_CH && idx < n) {
        row_ptr[idx] += boff;
        cursor[idx] = 1;
    }
    if (b == 0 && t == 0) row_ptr[n] = sh[SCAN_B - 1];
    if (b == 0 && t < NG) {
        int c = gstart[t + 1] - gstart[t];
        rcnt[t] = 1.0f / (float)max(c, 1);
    }
}

// CSR fill: eA = (src, f16 dinv[src]); eP = (src, f16 pool weight)
__global__ void k_build(const int* __restrict__ esrc, const int* __restrict__ edst,
                        const int* __restrict__ batch, const float* __restrict__ dinv,
                        const float* __restrict__ rcnt, const int* __restrict__ row_ptr,
                        int* __restrict__ cursor, uint32_t* __restrict__ eA,
                        uint32_t* __restrict__ eP, int n, int e) {
    int i = blockIdx.x * blockDim.x + threadIdx.x;
    if (i < n) {
        int p = row_ptr[i];
        float di = dinv[i];
        eA[p] = pack_sw(i, di);
        eP[p] = pack_sw(i, di * di * rcnt[batch[i]]);
    } else if (i < n + e) {
        int ei = i - n;
        int d = edst[ei], s = esrc[ei];
        int p = atomicAdd(cursor + d, 1);
        int idx = row_ptr[d] + p;
        float ds = dinv[s];
        eA[idx] = pack_sw(s, ds);
        eP[idx] = pack_sw(s, dinv[d] * ds * rcnt[batch[d]]);
    }
}

// ---------------- layer-1 gather: 4 edges per wave-load (1 KB/instruction) ----
// lane: grp = lane>>4 (edge slot), fl = lane&15 (features fl*8..fl*8+7, 16 B).

__global__ __launch_bounds__(256) void k_agg(
        const unsigned short* __restrict__ xb, const int* __restrict__ row_ptr,
        const uint32_t* __restrict__ eA, const float* __restrict__ dinv,
        unsigned short* __restrict__ xa, int n) {
    int node = blockIdx.x * 4 + (threadIdx.x >> 6);
    if (node >= n) return;
    int lane = threadIdx.x & 63;
    int grp = lane >> 4, fl = lane & 15;
    float acc[8] = {};
    int beg = row_ptr[node], end = row_ptr[node + 1];
    for (int j = beg; j < end; j += 4) {
        int jj = j + grp;
        bool valid = jj < end;
        uint32_t ev = __builtin_nontemporal_load(eA + (valid ? jj : beg));
        int s; float w;
        unpack_sw(ev, s, w);
        if (!valid) w = 0.f;
        bf16x8 v = *(const bf16x8*)(xb + ((size_t)s << 7) + fl * 8);
#pragma unroll
        for (int k = 0; k < 8; ++k)
            acc[k] += w * bf2f((unsigned short)v[k]);
    }
#pragma unroll
    for (int k = 0; k < 8; ++k) {
        acc[k] += __shfl_xor(acc[k], 16);
        acc[k] += __shfl_xor(acc[k], 32);
    }
    if (lane < 16) {
        float di = dinv[node];
        uint4 o;
        o.x = (uint32_t)f2bf(di * acc[0]) | ((uint32_t)f2bf(di * acc[1]) << 16);
        o.y = (uint32_t)f2bf(di * acc[2]) | ((uint32_t)f2bf(di * acc[3]) << 16);
        o.z = (uint32_t)f2bf(di * acc[4]) | ((uint32_t)f2bf(di * acc[5]) << 16);
        o.w = (uint32_t)f2bf(di * acc[6]) | ((uint32_t)f2bf(di * acc[7]) << 16);
        *(uint4*)(xa + ((size_t)node << 7) + fl * 8) = o;
    }
}

// ---------------- MFMA GEMM: h1 = bf16(relu(xa @ W1 + b1)) ----------------

__global__ __launch_bounds__(256) void k_gemm_mfma(
        const unsigned short* __restrict__ A, const unsigned short* __restrict__ Bt,
        const float* __restrict__ bias, unsigned short* __restrict__ C, int M) {
    const int m0 = blockIdx.x * 64;
    const int w  = threadIdx.x >> 6;
    const int l  = threadIdx.x & 63;
    const int lr = l & 15;
    const int lk = l >> 4;  // 0..3
    const int n0 = blockIdx.y * 64 + w * 16;

    f32x4 acc[4] = {};
#pragma unroll
    for (int ks = 0; ks < 4; ++ks) {
        const int k0 = ks * 32;
        bf16x8 bfr = *(const bf16x8*)(Bt + (size_t)(n0 + lr) * FIN + k0 + lk * 8);
#pragma unroll
        for (int mi = 0; mi < 4; ++mi) {
            int row = m0 + mi * 16 + lr;
            row = min(row, M - 1);
            bf16x8 afr = *(const bf16x8*)(A + ((size_t)row << 7) + k0 + lk * 8);
            acc[mi] = __builtin_amdgcn_mfma_f32_16x16x32_bf16(afr, bfr, acc[mi], 0, 0, 0);
        }
    }
    float b = bias[n0 + lr];
#pragma unroll
    for (int mi = 0; mi < 4; ++mi) {
#pragma unroll
        for (int r = 0; r < 4; ++r) {
            int row = m0 + mi * 16 + lk * 4 + r;
            if (row < M) {
                float v = fmaxf(acc[mi][r] + b, 0.f);
                C[(size_t)row * HID + n0 + lr] = f2bf(v);
            }
        }
    }
}

// ---------------- layer2+pool: 2 edges per wave-load (1 KB/instruction) ----
// lane: half = lane>>5 (edge slot), fl = lane&31 (features fl*8..fl*8+7).

__global__ __launch_bounds__(256) void k_pool(
        const unsigned short* __restrict__ h1, const int* __restrict__ row_ptr,
        const int* __restrict__ gstart, const uint32_t* __restrict__ eP,
        float* __restrict__ pooled) {
    __shared__ float red[4][HID];
    const int g  = blockIdx.x >> 3;
    const int kb = blockIdx.x & 7;
    const int e0 = row_ptr[gstart[g]];
    const int e1 = row_ptr[gstart[g + 1]];
    const int len = e1 - e0;
    const int per = (len + 7) >> 3;
    const int s0  = e0 + kb * per;
    const int s1  = min(s0 + per, e1);
    const int lane = threadIdx.x & 63;
    const int wv   = threadIdx.x >> 6;
    const int half = lane >> 5, fl = lane & 31;

    float acc[8] = {};
    for (int j = s0 + wv * 2; j < s1; j += 8) {
        int jj = j + half;
        bool valid = jj < s1;
        uint32_t ev = __builtin_nontemporal_load(eP + (valid ? jj : s0));
        int s; float w;
        unpack_sw(ev, s, w);
        if (!valid) w = 0.f;
        bf16x8 v = *(const bf16x8*)(h1 + ((size_t)s << 8) + fl * 8);
#pragma unroll
        for (int k = 0; k < 8; ++k)
            acc[k] += w * bf2f((unsigned short)v[k]);
    }
#pragma unroll
    for (int k = 0; k < 8; ++k)
        acc[k] += __shfl_xor(acc[k], 32);
    if (lane < 32) {
#pragma unroll
        for (int k = 0; k < 8; ++k)
            red[wv][fl * 8 + k] = acc[k];
    }
    __syncthreads();
    int t = threadIdx.x;
    float v = red[0][t] + red[1][t] + red[2][t] + red[3][t];
    if (v != 0.f) atomicAdd(&pooled[g * HID + t], v);
}

// ---------------- emb = pooled @ W2 + b2, then heads ----------------

__global__ __launch_bounds__(128) void k_head(const float* __restrict__ pooled,
                                              const float* __restrict__ W2,
                                              const float* __restrict__ b2,
                                              const float* __restrict__ Wg,
                                              const float* __restrict__ bg,
                                              const float* __restrict__ Wf,
                                              const float* __restrict__ bf,
                                              float* __restrict__ out_emb,
                                              float* __restrict__ out_gl,
                                              float* __restrict__ out_fl) {
    __shared__ float p[HID];
    __shared__ float e[EMB];
    __shared__ float gl[NGRP];
    __shared__ int ps;
    int g = blockIdx.x, c = threadIdx.x;
    for (int i = c; i < HID; i += 128) p[i] = pooled[(size_t)g * HID + i];
    __syncthreads();
    float a = b2[c];
    for (int k = 0; k < HID; ++k) a += p[k] * W2[(size_t)k * EMB + c];
    e[c] = a;
    out_emb[(size_t)g * EMB + c] = a;
    __syncthreads();
    if (c < NGRP) {
        float s = bg[c];
        for (int d = 0; d < EMB; ++d) s += e[d] * Wg[d * NGRP + c];
        gl[c] = s;
        out_gl[g * NGRP + c] = s;
    }
    __syncthreads();
    if (c == 0) {
        int bi = 0;
        float bv = gl[0];
        for (int t2 = 1; t2 < NGRP; ++t2)
            if (gl[t2] > bv) { bv = gl[t2]; bi = t2; }
        ps = bi;
    }
    __syncthreads();
    int pr = ps;
    float s = bf[pr * NFAM + c];
    for (int d = 0; d < EMB; ++d) s += e[d] * Wf[((size_t)pr * EMB + d) * NFAM + c];
    out_fl[g * NFAM + c] = s;
}

// ---------------- launch ----------------

extern "C" void kernel_launch(void* const* d_in, const int* in_sizes, int n_in,
                              void* d_out, int out_size, void* d_ws, size_t ws_size,
                              hipStream_t stream) {
    const float* x   = (const float*)d_in[0];
    const int*   ei  = (const int*)d_in[1];
    const int*   bat = (const int*)d_in[2];
    const float* W1  = (const float*)d_in[3];
    const float* b1  = (const float*)d_in[4];
    const float* W2  = (const float*)d_in[5];
    const float* b2  = (const float*)d_in[6];
    const float* Wg  = (const float*)d_in[7];
    const float* bg  = (const float*)d_in[8];
    const float* Wf  = (const float*)d_in[9];
    const float* bf  = (const float*)d_in[10];

    float* out     = (float*)d_out;
    float* out_emb = out;                        // 256*128
    float* out_gl  = out + (size_t)NG * EMB;     // 256*16
    float* out_fl  = out_gl + (size_t)NG * NGRP; // 256*128

    char* w = (char*)d_ws;
    auto alloc = [&](size_t bytes) {
        char* p = w;
        w += (bytes + 255) & ~(size_t)255;
        return p;
    };
    int*            degi    = (int*)alloc((size_t)NN * 4);
    float*          dinv    = (float*)alloc((size_t)NN * 4);
    int*            row_ptr = (int*)alloc((size_t)(NN + 1) * 4);
    int*            cursor  = (int*)alloc((size_t)NN * 4);
    int*            bsum    = (int*)alloc((size_t)SCAN_B * 4);
    uint32_t*       eA      = (uint32_t*)alloc((size_t)NETOT * 4);
    uint32_t*       eP      = (uint32_t*)alloc((size_t)NETOT * 4);
    int*            gstart  = (int*)alloc((size_t)(NG + 1) * 4);
    float*          rcnt    = (float*)alloc((size_t)NG * 4);
    unsigned short* xb      = (unsigned short*)alloc((size_t)NN * FIN * 2);
    unsigned short* xa      = (unsigned short*)alloc((size_t)NN * FIN * 2);
    unsigned short* W1t     = (unsigned short*)alloc((size_t)HID * FIN * 2);
    unsigned short* h1      = (unsigned short*)alloc((size_t)NN * HID * 2);
    float*          pooled  = (float*)alloc((size_t)NG * HID * 4);

    const int* esrc = ei;
    const int* edst = ei + NE;

    k_init_deg<<<(NN + 255) / 256, 256, 0, stream>>>(degi, NN);
    k_count<<<(NE + 255) / 256, 256, 0, stream>>>(edst, degi, NE);
    k_prep<<<(NG * HID + 255) / 256, 256, 0, stream>>>(degi, bat, dinv, gstart,
                                                       pooled, NN, NG);
    k_xconv<<<(NN * FIN / 8 + 255) / 256, 256, 0, stream>>>(x, xb);
    k_w1t<<<(HID * FIN + 255) / 256, 256, 0, stream>>>(W1, W1t);
    k_scanA<<<SCAN_B, 256, 0, stream>>>(degi, row_ptr, bsum, NN);
    k_scanB<<<SCAN_B, 256, 0, stream>>>(bsum, gstart, rcnt, row_ptr, cursor, NN);
    k_build<<<(NETOT + 255) / 256, 256, 0, stream>>>(esrc, edst, bat, dinv, rcnt,
                                                     row_ptr, cursor, eA, eP, NN, NE);

    // layer 1
    k_agg<<<(NN + 3) / 4, 256, 0, stream>>>(xb, row_ptr, eA, dinv, xa, NN);
    {
        dim3 grid((NN + 63) / 64, HID / 64);
        k_gemm_mfma<<<grid, 256, 0, stream>>>(xa, W1t, b1, h1, NN);
    }

    // layer 2 + pool
    k_pool<<<NG * 8, 256, 0, stream>>>(h1, row_ptr, gstart, eP, pooled);

    // emb + heads
    k_head<<<NG, 128, 0, stream>>>(pooled, W2, b2, Wg, bg, Wf, bf,
                                   out_emb, out_gl, out_fl);
}

// Round 8
// 216.558 us; speedup vs baseline: 4.4776x; 1.1939x over previous
//
#include <hip/hip_runtime.h>
#include <hip/hip_fp16.h>
#include <cstddef>
#include <cstdint>

static constexpr int NN   = 50000;   // nodes
static constexpr int NE   = 800000;  // edges (without self loops)
static constexpr int NG   = 256;     // graphs
static constexpr int FIN  = 128;
static constexpr int HID  = 256;
static constexpr int EMB  = 128;
static constexpr int NGRP = 16;
static constexpr int NFAM = 128;
static constexpr int NETOT = NE + NN;  // edges + self loops

static constexpr int SCAN_B  = 256;
static constexpr int SCAN_CH = (NN + SCAN_B - 1) / SCAN_B;  // 196

using bf16x8 = __attribute__((ext_vector_type(8))) short;
using f32x4  = __attribute__((ext_vector_type(4))) float;

__device__ __forceinline__ unsigned short f2bf(float f) {
    uint32_t u = __float_as_uint(f);
    u += 0x7FFFu + ((u >> 16) & 1u);
    return (unsigned short)(u >> 16);
}
__device__ __forceinline__ float bf2f(unsigned short u) {
    return __uint_as_float((uint32_t)u << 16);
}
// packed edge: low16 = src node, high16 = fp16 weight
__device__ __forceinline__ uint32_t pack_sw(int s, float w) {
    return (uint32_t)s | ((uint32_t)__half_as_ushort(__float2half(w)) << 16);
}
__device__ __forceinline__ void unpack_sw(uint32_t v, int& s, float& w) {
    s = (int)(v & 0xFFFFu);
    w = __half2float(__ushort_as_half((unsigned short)(v >> 16)));
}

// ---------------- setup ----------------

__global__ void k_init_deg(int* __restrict__ degi, int n) {
    int i = blockIdx.x * blockDim.x + threadIdx.x;
    if (i < n) degi[i] = 1;  // self loop
}

__global__ void k_count(const int* __restrict__ edst, int* __restrict__ degi, int e) {
    int i = blockIdx.x * blockDim.x + threadIdx.x;
    if (i < e) atomicAdd(degi + edst[i], 1);
}

// dinv + gstart + zero(emb_acc)
__global__ void k_prep(const int* __restrict__ degi, const int* __restrict__ batch,
                       float* __restrict__ dinv, int* __restrict__ gstart,
                       float* __restrict__ emb_acc, int n, int G) {
    int i = blockIdx.x * blockDim.x + threadIdx.x;   // 0..65535
    if (i < NG * EMB) emb_acc[i] = 0.f;
    if (i >= n) return;
    dinv[i] = rsqrtf((float)degi[i]);
    int b  = batch[i];
    int pb = (i == 0) ? -1 : batch[i - 1];
    for (int g = pb + 1; g <= b; ++g) gstart[g] = i;
    if (i == n - 1) {
        for (int g = b + 1; g <= G; ++g) gstart[g] = n;
    }
}

// xs = bf16(dinv[node] * x), vectorized 8/thread
__global__ void k_xconv(const float* __restrict__ x, const float* __restrict__ dinv,
                        unsigned short* __restrict__ xs) {
    int t = blockIdx.x * blockDim.x + threadIdx.x;   // NN*16 threads
    size_t i = (size_t)t * 8;
    float dv = dinv[t >> 4];
    float4 a = *(const float4*)(x + i);
    float4 b = *(const float4*)(x + i + 4);
    uint4 o;
    o.x = (uint32_t)f2bf(dv * a.x) | ((uint32_t)f2bf(dv * a.y) << 16);
    o.y = (uint32_t)f2bf(dv * a.z) | ((uint32_t)f2bf(dv * a.w) << 16);
    o.z = (uint32_t)f2bf(dv * b.x) | ((uint32_t)f2bf(dv * b.y) << 16);
    o.w = (uint32_t)f2bf(dv * b.z) | ((uint32_t)f2bf(dv * b.w) << 16);
    *(uint4*)(xs + i) = o;
}

// W1 [128][256] fp32 -> W1t [256][128] bf16
__global__ void k_w1t(const float* __restrict__ W1, unsigned short* __restrict__ W1t) {
    int t = blockIdx.x * blockDim.x + threadIdx.x;  // 0..32767
    int nidx = t >> 7, k = t & 127;
    W1t[t] = f2bf(W1[(size_t)k * HID + nidx]);
}

// W2 [256][128] fp32 -> W2t [128][256] bf16
__global__ void k_w2t(const float* __restrict__ W2, unsigned short* __restrict__ W2t) {
    int t = blockIdx.x * blockDim.x + threadIdx.x;  // 0..32767
    int nidx = t >> 8, k = t & 255;
    W2t[t] = f2bf(W2[(size_t)k * EMB + nidx]);
}

// ---------------- parallel scan (2 kernels) ----------------

__global__ __launch_bounds__(256) void k_scanA(const int* __restrict__ degi,
                                               int* __restrict__ row_ptr,
                                               int* __restrict__ bsum, int n) {
    __shared__ int sh[256];
    const int b = blockIdx.x, t = threadIdx.x;
    const int idx = b * SCAN_CH + t;
    int v = 0;
    if (t < SCAN_CH && idx < n) v = degi[idx];
    sh[t] = v;
    __syncthreads();
    for (int off = 1; off < 256; off <<= 1) {
        int y = (t >= off) ? sh[t - off] : 0;
        __syncthreads();
        if (t >= off) sh[t] += y;
        __syncthreads();
    }
    if (t < SCAN_CH && idx < n) row_ptr[idx] = sh[t] - v;  // exclusive
    if (t == 255) bsum[b] = sh[255];
}

__global__ __launch_bounds__(256) void k_scanB(const int* __restrict__ bsum,
                                               const int* __restrict__ gstart,
                                               float* __restrict__ rcnt,
                                               int* __restrict__ row_ptr,
                                               int* __restrict__ cursor, int n) {
    __shared__ int sh[SCAN_B];
    const int b = blockIdx.x, t = threadIdx.x;
    sh[t] = bsum[t];
    __syncthreads();
    for (int off = 1; off < SCAN_B; off <<= 1) {
        int y = (t >= off) ? sh[t - off] : 0;
        __syncthreads();
        if (t >= off) sh[t] += y;
        __syncthreads();
    }
    const int boff = (b == 0) ? 0 : sh[b - 1];
    const int idx  = b * SCAN_CH + t;
    if (t < SCAN_CH && idx < n) {
        row_ptr[idx] += boff;
        cursor[idx] = 1;
    }
    if (b == 0 && t == 0) row_ptr[n] = sh[SCAN_B - 1];
    if (b == 0 && t < NG) {
        int c = gstart[t + 1] - gstart[t];
        rcnt[t] = 1.0f / (float)max(c, 1);
    }
}

// CSR fill: eA = src col (dinv_s folded into xs); eP = (src, f16 dinv_d*rcnt_g)
__global__ void k_build(const int* __restrict__ esrc, const int* __restrict__ edst,
                        const int* __restrict__ batch, const float* __restrict__ dinv,
                        const float* __restrict__ rcnt, const int* __restrict__ row_ptr,
                        int* __restrict__ cursor, int* __restrict__ eA,
                        uint32_t* __restrict__ eP, int n, int e) {
    int i = blockIdx.x * blockDim.x + threadIdx.x;
    if (i < n) {
        int p = row_ptr[i];
        eA[p] = i;
        eP[p] = pack_sw(i, dinv[i] * rcnt[batch[i]]);
    } else if (i < n + e) {
        int ei = i - n;
        int d = edst[ei], s = esrc[ei];
        int p = atomicAdd(cursor + d, 1);
        int idx = row_ptr[d] + p;
        eA[idx] = s;
        eP[idx] = pack_sw(s, dinv[d] * rcnt[batch[d]]);
    }
}

// ---------------- layer-1 gather: xa[i] = bf16(dinv_i * sum_j xs[col_j]) ----
// 4 edges per wave-load: grp = lane>>4 edge slot, fl = lane&15 (16 B features).

__global__ __launch_bounds__(256) void k_agg(
        const unsigned short* __restrict__ xs, const int* __restrict__ row_ptr,
        const int* __restrict__ eA, const float* __restrict__ dinv,
        unsigned short* __restrict__ xa, int n) {
    int node = blockIdx.x * 4 + (threadIdx.x >> 6);
    if (node >= n) return;
    int lane = threadIdx.x & 63;
    int grp = lane >> 4, fl = lane & 15;
    float acc[8] = {};
    int beg = row_ptr[node], end = row_ptr[node + 1];
    for (int j = beg; j < end; j += 4) {
        int jj = j + grp;
        bool valid = jj < end;
        int s = __builtin_nontemporal_load(eA + (valid ? jj : beg));
        float m = valid ? 1.f : 0.f;
        bf16x8 v = *(const bf16x8*)(xs + ((size_t)s << 7) + fl * 8);
#pragma unroll
        for (int k = 0; k < 8; ++k)
            acc[k] += m * bf2f((unsigned short)v[k]);
    }
#pragma unroll
    for (int k = 0; k < 8; ++k) {
        acc[k] += __shfl_xor(acc[k], 16);
        acc[k] += __shfl_xor(acc[k], 32);
    }
    if (lane < 16) {
        float di = dinv[node];
        uint4 o;
        o.x = (uint32_t)f2bf(di * acc[0]) | ((uint32_t)f2bf(di * acc[1]) << 16);
        o.y = (uint32_t)f2bf(di * acc[2]) | ((uint32_t)f2bf(di * acc[3]) << 16);
        o.z = (uint32_t)f2bf(di * acc[4]) | ((uint32_t)f2bf(di * acc[5]) << 16);
        o.w = (uint32_t)f2bf(di * acc[6]) | ((uint32_t)f2bf(di * acc[7]) << 16);
        *(uint4*)(xa + ((size_t)node << 7) + fl * 8) = o;
    }
}

// ---------------- fused GEMM: H = bf16( dinv_row * relu(xa@W1+b1) @ W2 ) ----
// stage1 64x256 -> LDS (XOR-swizzled); stage2 64x128 from LDS; coalesced store.

__global__ __launch_bounds__(256) void k_fgemm(
        const unsigned short* __restrict__ A,   // xa [M][128]
        const unsigned short* __restrict__ W1t, // [256][128]
        const unsigned short* __restrict__ W2t, // [128][256]
        const float* __restrict__ b1, const float* __restrict__ dinv,
        unsigned short* __restrict__ H, int M) {
    __shared__ unsigned short h1s[64 * 256];  // 32 KB
    const int m0 = blockIdx.x * 64;
    const int w  = threadIdx.x >> 6;
    const int l  = threadIdx.x & 63;
    const int lr = l & 15;
    const int lk = l >> 4;  // 0..3

    // stage 1: cols w*64 .. w*64+63
    {
        f32x4 acc[4][4] = {};
        const int n0 = w * 64;
#pragma unroll
        for (int ks = 0; ks < 4; ++ks) {
            const int k0 = ks * 32 + lk * 8;
            bf16x8 bfr[4];
#pragma unroll
            for (int ni = 0; ni < 4; ++ni)
                bfr[ni] = *(const bf16x8*)(W1t + (size_t)(n0 + ni * 16 + lr) * FIN + k0);
#pragma unroll
            for (int mi = 0; mi < 4; ++mi) {
                int row = min(m0 + mi * 16 + lr, M - 1);
                bf16x8 afr = *(const bf16x8*)(A + ((size_t)row << 7) + k0);
#pragma unroll
                for (int ni = 0; ni < 4; ++ni)
                    acc[mi][ni] = __builtin_amdgcn_mfma_f32_16x16x32_bf16(
                        afr, bfr[ni], acc[mi][ni], 0, 0, 0);
            }
        }
#pragma unroll
        for (int ni = 0; ni < 4; ++ni) {
            int col = n0 + ni * 16 + lr;
            float bb = b1[col];
#pragma unroll
            for (int mi = 0; mi < 4; ++mi) {
#pragma unroll
                for (int r = 0; r < 4; ++r) {
                    int rl = mi * 16 + lk * 4 + r;
                    float dv = dinv[min(m0 + rl, M - 1)];
                    float v = fmaxf(acc[mi][ni][r] + bb, 0.f) * dv;
                    int byte = (rl * 512 + col * 2) ^ ((rl & 7) << 4);
                    *(unsigned short*)((char*)h1s + byte) = f2bf(v);
                }
            }
        }
    }
    __syncthreads();
    // stage 2: cols w*32 .. w*32+31, K=256 from LDS
    f32x4 acc2[4][2] = {};
    {
        const int n0 = w * 32;
#pragma unroll
        for (int ks = 0; ks < 8; ++ks) {
            const int k0 = ks * 32 + lk * 8;
            bf16x8 bfr[2];
#pragma unroll
            for (int ni = 0; ni < 2; ++ni)
                bfr[ni] = *(const bf16x8*)(W2t + (size_t)(n0 + ni * 16 + lr) * HID + k0);
#pragma unroll
            for (int mi = 0; mi < 4; ++mi) {
                int rl = mi * 16 + lr;
                int byte = (rl * 512 + k0 * 2) ^ ((rl & 7) << 4);
                bf16x8 afr = *(const bf16x8*)((const char*)h1s + byte);
#pragma unroll
                for (int ni = 0; ni < 2; ++ni)
                    acc2[mi][ni] = __builtin_amdgcn_mfma_f32_16x16x32_bf16(
                        afr, bfr[ni], acc2[mi][ni], 0, 0, 0);
            }
        }
    }
    __syncthreads();  // all LDS reads done before reuse
    {
        const int n0 = w * 32;
#pragma unroll
        for (int ni = 0; ni < 2; ++ni) {
            int col = n0 + ni * 16 + lr;
#pragma unroll
            for (int mi = 0; mi < 4; ++mi)
#pragma unroll
                for (int r = 0; r < 4; ++r) {
                    int rl = mi * 16 + lk * 4 + r;
                    h1s[rl * EMB + col] = f2bf(acc2[mi][ni][r]);
                }
        }
    }
    __syncthreads();
    // coalesced store: rows m0..m0+nrows, 128 bf16 each (16 x 16B chunks)
    int nrows = min(64, M - m0);
    for (int c = threadIdx.x; c < nrows * 16; c += 256) {
        int rl = c >> 4, cc = c & 15;
        *(uint4*)(H + ((size_t)(m0 + rl) << 7) + cc * 8) =
            *(const uint4*)(h1s + rl * EMB + cc * 8);
    }
}

// ---------------- pool: emb_acc[g] += sum_e w_e * H[src_e]  (128 feats) ----
// 8 blocks/graph; 4 edges per wave-load (grp=lane>>4, fl=lane&15, 16 B).

__global__ __launch_bounds__(256) void k_pool(
        const unsigned short* __restrict__ H, const int* __restrict__ row_ptr,
        const int* __restrict__ gstart, const uint32_t* __restrict__ eP,
        float* __restrict__ emb_acc) {
    __shared__ float red[4][EMB];
    const int g  = blockIdx.x >> 3;
    const int kb = blockIdx.x & 7;
    const int e0 = row_ptr[gstart[g]];
    const int e1 = row_ptr[gstart[g + 1]];
    const int len = e1 - e0;
    const int per = (len + 7) >> 3;
    const int s0  = e0 + kb * per;
    const int s1  = min(s0 + per, e1);
    const int lane = threadIdx.x & 63;
    const int wv   = threadIdx.x >> 6;
    const int grp = lane >> 4, fl = lane & 15;

    float acc[8] = {};
    for (int j = s0 + wv * 4; j < s1; j += 16) {
        int jj = j + grp;
        bool valid = jj < s1;
        uint32_t ev = __builtin_nontemporal_load(eP + (valid ? jj : s0));
        int s; float wgt;
        unpack_sw(ev, s, wgt);
        if (!valid) wgt = 0.f;
        bf16x8 v = *(const bf16x8*)(H + ((size_t)s << 7) + fl * 8);
#pragma unroll
        for (int k = 0; k < 8; ++k)
            acc[k] += wgt * bf2f((unsigned short)v[k]);
    }
#pragma unroll
    for (int k = 0; k < 8; ++k) {
        acc[k] += __shfl_xor(acc[k], 16);
        acc[k] += __shfl_xor(acc[k], 32);
    }
    if (lane < 16) {
#pragma unroll
        for (int k = 0; k < 8; ++k) red[wv][fl * 8 + k] = acc[k];
    }
    __syncthreads();
    int t = threadIdx.x;
    if (t < EMB) {
        float v = red[0][t] + red[1][t] + red[2][t] + red[3][t];
        if (v != 0.f) atomicAdd(&emb_acc[g * EMB + t], v);
    }
}

// ---------------- heads: emb = emb_acc + b2; group logits; argmax; family ----

__global__ __launch_bounds__(128) void k_head(const float* __restrict__ emb_acc,
                                              const int* __restrict__ gstart,
                                              const float* __restrict__ b2,
                                              const float* __restrict__ Wg,
                                              const float* __restrict__ bg,
                                              const float* __restrict__ Wf,
                                              const float* __restrict__ bff,
                                              float* __restrict__ out_emb,
                                              float* __restrict__ out_gl,
                                              float* __restrict__ out_fl) {
    __shared__ float e[EMB];
    __shared__ float gl[NGRP];
    __shared__ int ps;
    int g = blockIdx.x, c = threadIdx.x;
    bool nonempty = gstart[g + 1] > gstart[g];
    float a = emb_acc[g * EMB + c] + (nonempty ? b2[c] : 0.f);
    e[c] = a;
    out_emb[(size_t)g * EMB + c] = a;
    __syncthreads();
    if (c < NGRP) {
        float s = bg[c];
        for (int d = 0; d < EMB; ++d) s += e[d] * Wg[d * NGRP + c];
        gl[c] = s;
        out_gl[g * NGRP + c] = s;
    }
    __syncthreads();
    if (c == 0) {
        int bi = 0;
        float bv = gl[0];
        for (int t2 = 1; t2 < NGRP; ++t2)
            if (gl[t2] > bv) { bv = gl[t2]; bi = t2; }
        ps = bi;
    }
    __syncthreads();
    int pr = ps;
    float s = bff[pr * NFAM + c];
    for (int d = 0; d < EMB; ++d) s += e[d] * Wf[((size_t)pr * EMB + d) * NFAM + c];
    out_fl[g * NFAM + c] = s;
}

// ---------------- launch ----------------

extern "C" void kernel_launch(void* const* d_in, const int* in_sizes, int n_in,
                              void* d_out, int out_size, void* d_ws, size_t ws_size,
                              hipStream_t stream) {
    const float* x   = (const float*)d_in[0];
    const int*   ei  = (const int*)d_in[1];
    const int*   bat = (const int*)d_in[2];
    const float* W1  = (const float*)d_in[3];
    const float* b1  = (const float*)d_in[4];
    const float* W2  = (const float*)d_in[5];
    const float* b2  = (const float*)d_in[6];
    const float* Wg  = (const float*)d_in[7];
    const float* bg  = (const float*)d_in[8];
    const float* Wf  = (const float*)d_in[9];
    const float* bf  = (const float*)d_in[10];

    float* out     = (float*)d_out;
    float* out_emb = out;                        // 256*128
    float* out_gl  = out + (size_t)NG * EMB;     // 256*16
    float* out_fl  = out_gl + (size_t)NG * NGRP; // 256*128

    char* w = (char*)d_ws;
    auto alloc = [&](size_t bytes) {
        char* p = w;
        w += (bytes + 255) & ~(size_t)255;
        return p;
    };
    int*            degi    = (int*)alloc((size_t)NN * 4);
    float*          dinv    = (float*)alloc((size_t)NN * 4);
    int*            row_ptr = (int*)alloc((size_t)(NN + 1) * 4);
    int*            cursor  = (int*)alloc((size_t)NN * 4);
    int*            bsum    = (int*)alloc((size_t)SCAN_B * 4);
    int*            eA      = (int*)alloc((size_t)NETOT * 4);
    uint32_t*       eP      = (uint32_t*)alloc((size_t)NETOT * 4);
    int*            gstart  = (int*)alloc((size_t)(NG + 1) * 4);
    float*          rcnt    = (float*)alloc((size_t)NG * 4);
    unsigned short* xs      = (unsigned short*)alloc((size_t)NN * FIN * 2);
    unsigned short* xa      = (unsigned short*)alloc((size_t)NN * FIN * 2);
    unsigned short* W1t     = (unsigned short*)alloc((size_t)HID * FIN * 2);
    unsigned short* W2t     = (unsigned short*)alloc((size_t)EMB * HID * 2);
    unsigned short* H       = (unsigned short*)alloc((size_t)NN * EMB * 2);
    float*          emb_acc = (float*)alloc((size_t)NG * EMB * 4);

    const int* esrc = ei;
    const int* edst = ei + NE;

    k_init_deg<<<(NN + 255) / 256, 256, 0, stream>>>(degi, NN);
    k_count<<<(NE + 255) / 256, 256, 0, stream>>>(edst, degi, NE);
    k_prep<<<(NG * HID + 255) / 256, 256, 0, stream>>>(degi, bat, dinv, gstart,
                                                       emb_acc, NN, NG);
    k_xconv<<<(NN * 16) / 256, 256, 0, stream>>>(x, dinv, xs);
    k_w1t<<<(HID * FIN) / 256, 256, 0, stream>>>(W1, W1t);
    k_w2t<<<(EMB * HID) / 256, 256, 0, stream>>>(W2, W2t);
    k_scanA<<<SCAN_B, 256, 0, stream>>>(degi, row_ptr, bsum, NN);
    k_scanB<<<SCAN_B, 256, 0, stream>>>(bsum, gstart, rcnt, row_ptr, cursor, NN);
    k_build<<<(NETOT + 255) / 256, 256, 0, stream>>>(esrc, edst, bat, dinv, rcnt,
                                                     row_ptr, cursor, eA, eP, NN, NE);

    // layer 1 gather + fused (W1 -> relu -> W2, dinv_s folded) projection
    k_agg<<<(NN + 3) / 4, 256, 0, stream>>>(xs, row_ptr, eA, dinv, xa, NN);
    k_fgemm<<<(NN + 63) / 64, 256, 0, stream>>>(xa, W1t, W2t, b1, dinv, H, NN);

    // pool over graph-contiguous edges (128-feat rows)
    k_pool<<<NG * 8, 256, 0, stream>>>(H, row_ptr, gstart, eP, emb_acc);

    // heads
    k_head<<<NG, 128, 0, stream>>>(emb_acc, gstart, b2, Wg, bg, Wf, bf,
                                   out_emb, out_gl, out_fl);
}